// Round 8
// baseline (215.942 us; speedup 1.0000x reference)
//
#include <hip/hip_runtime.h>

#define NT 256
#define RCHUNK 32
#define NSLOT 32

typedef float f2 __attribute__((ext_vector_type(2)));
typedef int   i2 __attribute__((ext_vector_type(2)));

__device__ __forceinline__ float bload32(__amdgpu_buffer_rsrc_t r, int voff) {
    return __builtin_bit_cast(float, __builtin_amdgcn_raw_buffer_load_b32(r, voff, 0, 0));
}
__device__ __forceinline__ f2 bload64(__amdgpu_buffer_rsrc_t r, int voff) {
    return __builtin_bit_cast(f2, __builtin_amdgcn_raw_buffer_load_b64(r, voff, 0, 0));
}

__device__ __forceinline__ float ccval(float sI, float sJ, float sII, float sJJ,
                                       float sIJ, float inv_ws) {
    float cross = fmaf(-(sI * sJ), inv_ws, sIJ);
    float iv    = fmaf(-(sI * sI), inv_ws, sII);
    float jv    = fmaf(-(sJ * sJ), inv_ws, sJJ);
    float den   = fmaf(iv, jv, 1e-8f);
    return (cross * cross) * __builtin_amdgcn_rcpf(den);
}

// Wave-autonomous, ZERO-LDS: each 64-lane wave owns 64 cols x RCHUNK rows.
// Each lane loads its own WIN-tap window straight from global through a
// per-row SRD (num_records = row bytes): horizontal AND row OOB -> 0 in HW.
// No barriers/fences anywhere; vertical 5-stat window in a register ring.
template<int W, int WIN, int S>
__device__ void level_wave(const float* __restrict__ yh,
                           const float* __restrict__ y,
                           int sub, float* __restrict__ ws_acc, int level, int wid)
{
    constexpr int HW = WIN / 2;
    constexpr int T  = RCHUNK + 2 * HW;
    constexpr int G  = (T + WIN - 1) / WIN;
    constexpr int OFF = (S - 2) / 2;
    constexpr float INV_WS = 1.0f / (float)(WIN * WIN);
    constexpr int STRIPS = W / 64;
    constexpr int CHUNKS = W / RCHUNK;

    int b     = sub / (STRIPS * CHUNKS);
    int rem   = sub - b * (STRIPS * CHUNKS);
    int chunk = rem / STRIPS;
    int strip = rem - chunk * STRIPS;
    int r0 = chunk * RCHUNK;
    int c0 = strip * 64;

    const float* Jb = yh + (size_t)b * W * W;
    const float* Yb = y  + (size_t)b * 512 * 512;

    int l = threadIdx.x & 63;
    // byte voffsets for tap 0 (negative col wraps to huge unsigned -> OOB -> 0)
    int vJ0 = (c0 + l - HW) * 4;
    int vY0 = (S * (c0 + l - HW) + OFF) * 4;   // S>=2 only

    float rI[WIN], rJ[WIN], rII[WIN], rJJ[WIN], rIJ[WIN];
#pragma unroll
    for (int k = 0; k < WIN; ++k) { rI[k]=0.f; rJ[k]=0.f; rII[k]=0.f; rJJ[k]=0.f; rIJ[k]=0.f; }
    float vI=0.f, vJ=0.f, vII=0.f, vJJ=0.f, vIJ=0.f;
    float l2acc = 0.f, ccacc = 0.f;

    for (int g = 0; g < G; ++g) {
#pragma unroll
        for (int u = 0; u < WIN; ++u) {
            int rr = g * WIN + u;          // wave-uniform
            if (rr < T) {
                int r = r0 - HW + rr;
                bool valid = (r >= 0) && (r < W);
                int nrecJ = valid ? W * 4 : 0;
                int nrecY = valid ? 512 * 4 : 0;

                auto rsJ = __builtin_amdgcn_make_buffer_rsrc(
                    (void*)(Jb + (long)r * W), (short)0, nrecJ, 0x00020000);

                float qJ[WIN], qI[WIN];
#pragma unroll
                for (int k = 0; k < WIN; ++k)
                    qJ[k] = bload32(rsJ, vJ0 + 4 * k);

                if constexpr (S == 1) {
                    auto rsI = __builtin_amdgcn_make_buffer_rsrc(
                        (void*)(Yb + (long)r * 512), (short)0, nrecY, 0x00020000);
#pragma unroll
                    for (int k = 0; k < WIN; ++k)
                        qI[k] = bload32(rsI, vJ0 + 4 * k);
                } else {
                    int yr = S * r + OFF;
                    auto rsA = __builtin_amdgcn_make_buffer_rsrc(
                        (void*)(Yb + (long)yr * 512), (short)0, nrecY, 0x00020000);
                    auto rsB = __builtin_amdgcn_make_buffer_rsrc(
                        (void*)(Yb + (long)(yr + 1) * 512), (short)0, nrecY, 0x00020000);
                    if constexpr (S == 2) {
#pragma unroll
                        for (int k = 0; k < WIN; ++k) {
                            f2 pa = bload64(rsA, vY0 + 8 * k);   // 8-aligned: vY0 % 8 == 0
                            f2 pb = bload64(rsB, vY0 + 8 * k);
                            qI[k] = 0.25f * ((pa.x + pa.y) + (pb.x + pb.y));
                        }
                    } else {
#pragma unroll
                        for (int k = 0; k < WIN; ++k) {
                            float a0 = bload32(rsA, vY0 + 4 * S * k);
                            float a1 = bload32(rsA, vY0 + 4 * S * k + 4);
                            float b0 = bload32(rsB, vY0 + 4 * S * k);
                            float b1 = bload32(rsB, vY0 + 4 * S * k + 4);
                            qI[k] = 0.25f * ((a0 + a1) + (b0 + b1));
                        }
                    }
                }

                float sI=0.f, sJ=0.f, sII=0.f, sJJ=0.f, sIJ=0.f;
#pragma unroll
                for (int k = 0; k < WIN; ++k) {
                    sI += qI[k]; sJ += qJ[k];
                    sII = fmaf(qI[k], qI[k], sII);
                    sJJ = fmaf(qJ[k], qJ[k], sJJ);
                    sIJ = fmaf(qI[k], qJ[k], sIJ);
                }
                if (rr >= HW && rr < HW + RCHUNK) {
                    float d = qJ[HW] - qI[HW];
                    l2acc = fmaf(d, d, l2acc);
                }
                rI[u]=sI; rJ[u]=sJ; rII[u]=sII; rJJ[u]=sJJ; rIJ[u]=sIJ;
                vI+=sI; vJ+=sJ; vII+=sII; vJJ+=sJJ; vIJ+=sIJ;
                if (rr >= 2 * HW) {
                    ccacc += ccval(vI, vJ, vII, vJJ, vIJ, INV_WS);
                    const int uo = (u + 1) % WIN;   // compile-time after unroll
                    vI-=rI[uo]; vJ-=rJ[uo]; vII-=rII[uo]; vJJ-=rJJ[uo]; vIJ-=rIJ[uo];
                }
            }
        }
    }

#pragma unroll
    for (int off = 32; off > 0; off >>= 1) {
        l2acc += __shfl_down(l2acc, off);
        ccacc += __shfl_down(ccacc, off);
    }
    if (l == 0) {
        int slot = wid & (NSLOT - 1);
        atomicAdd(&ws_acc[(level * 2 + 0) * NSLOT + slot], l2acc);
        atomicAdd(&ws_acc[(level * 2 + 1) * NSLOT + slot], ccacc);
    }
}

__global__ __launch_bounds__(NT)
void hier_loss_kernel(const float* __restrict__ yh0, const float* __restrict__ yh1,
                      const float* __restrict__ yh2, const float* __restrict__ yh3,
                      const float* __restrict__ y, float* ws_acc)
{
    int wid = blockIdx.x * (NT / 64) + (threadIdx.x >> 6);
    // L0: 8 strips x 16 chunks x 32 = 4096 | L1: 4x8x32=1024 -> [4096,5120)
    // L2: 2x4x32=256 -> [5120,5376)       | L3: 1x2x32=64   -> [5376,5440)
    if (wid < 4096) {
        level_wave<512, 9, 1>(yh0, y, wid, ws_acc, 0, wid);
    } else if (wid < 5120) {
        level_wave<256, 9, 2>(yh1, y, wid - 4096, ws_acc, 1, wid);
    } else if (wid < 5376) {
        level_wave<128, 7, 4>(yh2, y, wid - 5120, ws_acc, 2, wid);
    } else {
        level_wave<64, 5, 8>(yh3, y, wid - 5376, ws_acc, 3, wid);
    }
}

__global__ void hier_finalize_kernel(const float* __restrict__ ws_acc, float* __restrict__ out)
{
    if (threadIdx.x == 0 && blockIdx.x == 0) {
        const float wts[4] = {1.0f, 0.5f, 0.25f, 0.125f};
        float total = 0.f;
#pragma unroll
        for (int lv = 0; lv < 4; ++lv) {
            float l2s = 0.f, ccs = 0.f;
            for (int s = 0; s < NSLOT; ++s) {
                l2s += ws_acc[(lv * 2 + 0) * NSLOT + s];
                ccs += ws_acc[(lv * 2 + 1) * NSLOT + s];
            }
            float l2  = l2s / 32.0f;
            float ncc = -ccs / (32.0f * 100.0f);
            float ll  = wts[lv] * (l2 + ncc) * 0.5f;
            out[1 + lv] = ll;
            total += ll;
        }
        out[0] = total;
    }
}

extern "C" void kernel_launch(void* const* d_in, const int* in_sizes, int n_in,
                              void* d_out, int out_size, void* d_ws, size_t ws_size,
                              hipStream_t stream)
{
    const float* yh0 = (const float*)d_in[0];
    const float* yh1 = (const float*)d_in[1];
    const float* yh2 = (const float*)d_in[2];
    const float* yh3 = (const float*)d_in[3];
    const float* y   = (const float*)d_in[4];
    float* ws_acc = (float*)d_ws;
    float* out = (float*)d_out;

    hipMemsetAsync(ws_acc, 0, 8 * NSLOT * sizeof(float), stream);
    hier_loss_kernel<<<5440 / (NT / 64), NT, 0, stream>>>(yh0, yh1, yh2, yh3, y, ws_acc);
    hier_finalize_kernel<<<1, 64, 0, stream>>>(ws_acc, out);
}

// Round 9
// 117.560 us; speedup vs baseline: 1.8369x; 1.8369x over previous
//
#include <hip/hip_runtime.h>

#define NT 256
#define RCHUNK 32
#define NSLOT 32
#define RWA 272   // staged-row pair stride (max RW=264, rounded up)

typedef float f2 __attribute__((ext_vector_type(2)));

__device__ __forceinline__ float ccval(float sI, float sJ, float sII, float sJJ,
                                       float sIJ, float inv_ws) {
    float cross = fmaf(-(sI * sJ), inv_ws, sIJ);
    float iv    = fmaf(-(sI * sI), inv_ws, sII);
    float jv    = fmaf(-(sJ * sJ), inv_ws, sJJ);
    float den   = fmaf(iv, jv, 1e-8f);
    return (cross * cross) * __builtin_amdgcn_rcpf(den);
}

// Block = CW cols x RCHUNK rows. Phase = WIN rows (ring BASE always 0).
// Reg-staged rows -> interleaved {I,J} pairs in LDS (1 ds_read_b64 per tap).
// Raw s_barrier + lgkmcnt(0) ONLY: fetch(k+1) stays in flight across the
// barrier and is consumed by next phase's ds_write (full-phase hiding).
template<int W, int WIN, int S, int CW>
__device__ void level_block(const float* __restrict__ yh,
                            const float* __restrict__ y,
                            int sub, float* __restrict__ ws_acc, int level,
                            float* __restrict__ sm)
{
    constexpr int HW  = WIN / 2;
    constexpr int RW  = CW + 2 * HW;              // staged pairs per row
    constexpr int T   = RCHUNK + 2 * HW;
    constexpr int NPH = (T + WIN - 1) / WIN;
    constexpr int OFF = (S - 2) / 2;
    constexpr int WRAP = (RW > NT) ? (RW - NT) : 0;
    constexpr float INV_WS = 1.0f / (float)(WIN * WIN);
    constexpr int STRIPS = W / CW;
    constexpr int CHUNKS = W / RCHUNK;

    int b     = sub / (STRIPS * CHUNKS);
    int rem   = sub - b * (STRIPS * CHUNKS);
    int chunk = rem / STRIPS;
    int strip = rem - chunk * STRIPS;
    int r0 = chunk * RCHUNK;
    int c0 = strip * CW;

    const float* Jb = yh + (size_t)b * W * W;
    const float* Yb = y  + (size_t)b * 512 * 512;
    int t = threadIdx.x;
    int colA = c0 - HW + t;
    int colB = colA + NT;

    float fI[WIN], fJ[WIN], gI[WIN], gJ[WIN];   // staged phase rows (+wrap)

    auto fetch_one = [&](int rr, int col, float& I, float& J) {
        I = 0.f; J = 0.f;
        int r = r0 - HW + rr;
        if (rr < T && r >= 0 && r < W && col >= 0 && col < W) {
            J = Jb[(long)r * W + col];
            if constexpr (S == 1) {
                I = Yb[(long)r * 512 + col];
            } else if constexpr (S == 2) {
                const float* p = Yb + (long)(2 * r) * 512 + 2 * col;
                f2 a = *(const f2*)p;
                f2 c = *(const f2*)(p + 512);
                I = 0.25f * ((a.x + a.y) + (c.x + c.y));
            } else {
                const float* p = Yb + (long)(S * r + OFF) * 512 + (S * col + OFF);
                I = 0.25f * ((p[0] + p[1]) + (p[512] + p[513]));
            }
        }
    };

    auto fetch_phase = [&](int k) {
#pragma unroll
        for (int p = 0; p < WIN; ++p) {
            int rr = k * WIN + p;
            if (t < RW) fetch_one(rr, colA, fI[p], fJ[p]);
            if constexpr (WRAP > 0) {
                if (t < WRAP) fetch_one(rr, colB, gI[p], gJ[p]);
            }
        }
    };

    auto write_phase = [&](int k) {
#pragma unroll
        for (int p = 0; p < WIN; ++p) {
            float* base = sm + 2 * (size_t)(((k & 1) * WIN + p) * RWA);
            if (t < RW) { f2 v = {fI[p], fJ[p]}; *(f2*)(base + 2 * t) = v; }
            if constexpr (WRAP > 0) {
                if (t < WRAP) { f2 v = {gI[p], gJ[p]}; *(f2*)(base + 2 * (t + NT)) = v; }
            }
        }
    };

    float rI[WIN], rJ[WIN], rII[WIN], rJJ[WIN], rIJ[WIN];
#pragma unroll
    for (int k = 0; k < WIN; ++k) { rI[k]=0.f; rJ[k]=0.f; rII[k]=0.f; rJJ[k]=0.f; rIJ[k]=0.f; }
    float vI=0.f, vJ=0.f, vII=0.f, vJJ=0.f, vIJ=0.f;
    float l2acc = 0.f, ccacc = 0.f;

    fetch_phase(0);

    for (int k = 0; k < NPH; ++k) {
        write_phase(k);
        if (k + 1 < NPH) fetch_phase(k + 1);   // in flight across the barrier
        asm volatile("s_waitcnt lgkmcnt(0)" ::: "memory");
        __builtin_amdgcn_s_barrier();          // NO vmcnt drain here
        // compute phase k
#pragma unroll
        for (int u = 0; u < WIN; ++u) {
            int rr = k * WIN + u;
            if (t < CW && rr < T) {
                const float* base = sm + 2 * (size_t)(((k & 1) * WIN + u) * RWA);
                float sI=0.f, sJ=0.f, sII=0.f, sJJ=0.f, sIJ=0.f, Ic=0.f, Jc=0.f;
#pragma unroll
                for (int kk = 0; kk < WIN; ++kk) {
                    f2 v = *(const f2*)(base + 2 * (t + kk));
                    float I = v.x, J = v.y;
                    if (kk == HW) { Ic = I; Jc = J; }
                    sI += I; sJ += J;
                    sII = fmaf(I, I, sII);
                    sJJ = fmaf(J, J, sJJ);
                    sIJ = fmaf(I, J, sIJ);
                }
                if (rr >= HW && rr < HW + RCHUNK) {
                    float d = Jc - Ic;
                    l2acc = fmaf(d, d, l2acc);
                }
                rI[u]=sI; rJ[u]=sJ; rII[u]=sII; rJJ[u]=sJJ; rIJ[u]=sIJ;
                vI+=sI; vJ+=sJ; vII+=sII; vJJ+=sJJ; vIJ+=sIJ;
                if (rr >= 2 * HW) {
                    ccacc += ccval(vI, vJ, vII, vJJ, vIJ, INV_WS);
                    const int uo = (u + 1) % WIN;   // compile-time after unroll
                    vI-=rI[uo]; vJ-=rJ[uo]; vII-=rII[uo]; vJJ-=rJJ[uo]; vIJ-=rIJ[uo];
                }
            }
        }
    }

#pragma unroll
    for (int off = 32; off > 0; off >>= 1) {
        l2acc += __shfl_down(l2acc, off);
        ccacc += __shfl_down(ccacc, off);
    }
    if ((t & 63) == 0) {
        int slot = (blockIdx.x * 4 + (t >> 6)) & (NSLOT - 1);
        atomicAdd(&ws_acc[(level * 2 + 0) * NSLOT + slot], l2acc);
        atomicAdd(&ws_acc[(level * 2 + 1) * NSLOT + slot], ccacc);
    }
}

__global__ __launch_bounds__(NT)
void hier_loss_kernel(const float* __restrict__ yh0, const float* __restrict__ yh1,
                      const float* __restrict__ yh2, const float* __restrict__ yh3,
                      const float* __restrict__ y, float* ws_acc)
{
    __shared__ float smem[2 * 9 * RWA * 2];   // 39,168 B
    int bid = blockIdx.x;
    // L0: 2 strips x 16 chunks x 32 = 1024 | L1: 1x8x32=256 -> [1024,1280)
    // L2: 1x4x32=128 -> [1280,1408)        | L3: 1x2x32=64  -> [1408,1472)
    if (bid < 1024) {
        level_block<512, 9, 1, 256>(yh0, y, bid, ws_acc, 0, smem);
    } else if (bid < 1280) {
        level_block<256, 9, 2, 256>(yh1, y, bid - 1024, ws_acc, 1, smem);
    } else if (bid < 1408) {
        level_block<128, 7, 4, 128>(yh2, y, bid - 1280, ws_acc, 2, smem);
    } else {
        level_block<64, 5, 8, 64>(yh3, y, bid - 1408, ws_acc, 3, smem);
    }
}

__global__ void hier_finalize_kernel(const float* __restrict__ ws_acc, float* __restrict__ out)
{
    if (threadIdx.x == 0 && blockIdx.x == 0) {
        const float wts[4] = {1.0f, 0.5f, 0.25f, 0.125f};
        float total = 0.f;
#pragma unroll
        for (int lv = 0; lv < 4; ++lv) {
            float l2s = 0.f, ccs = 0.f;
            for (int s = 0; s < NSLOT; ++s) {
                l2s += ws_acc[(lv * 2 + 0) * NSLOT + s];
                ccs += ws_acc[(lv * 2 + 1) * NSLOT + s];
            }
            float l2  = l2s / 32.0f;
            float ncc = -ccs / (32.0f * 100.0f);
            float ll  = wts[lv] * (l2 + ncc) * 0.5f;
            out[1 + lv] = ll;
            total += ll;
        }
        out[0] = total;
    }
}

extern "C" void kernel_launch(void* const* d_in, const int* in_sizes, int n_in,
                              void* d_out, int out_size, void* d_ws, size_t ws_size,
                              hipStream_t stream)
{
    const float* yh0 = (const float*)d_in[0];
    const float* yh1 = (const float*)d_in[1];
    const float* yh2 = (const float*)d_in[2];
    const float* yh3 = (const float*)d_in[3];
    const float* y   = (const float*)d_in[4];
    float* ws_acc = (float*)d_ws;
    float* out = (float*)d_out;

    hipMemsetAsync(ws_acc, 0, 8 * NSLOT * sizeof(float), stream);
    hier_loss_kernel<<<1472, NT, 0, stream>>>(yh0, yh1, yh2, yh3, y, ws_acc);
    hier_finalize_kernel<<<1, 64, 0, stream>>>(ws_acc, out);
}